// Round 9
// baseline (2046.619 us; speedup 1.0000x reference)
//
#include <hip/hip_runtime.h>
#include <math.h>

// KMeansGrouping: B=32, N=4096, D=256, K=24, 25 iters.
// Round 9: k_cluster -> streamed LDS-bucket kernel. One block per (256-pt
// chunk, batch); part[24][256] f64 in LDS (can't be spilled by the register
// allocator -- r4/r5 lesson: 24 f64 accumulators never stay in VGPRs). All 4
// waves stream rows ascending; wave w owns dims [64w,64w+64) so LDS rmw never
// collides and per-dim add order is strictly row-ascending (deterministic).
// No ballots, no 24x-redundant scans, coalesced sequential row loads.
// k_upd3: combine 16 chunks ascending + exact int counts from assign.
// Summands identical; order change = f64 reassociation (passed r4-r8).

#define BATCH 32
#define NPTS 4096
#define DIM 256
#define NSLOT 24
#define NITER 25
#define NCH 16
#define CPTS 256 // points per k_clusterS block

// ---------------- K0: per-point inverse norm (f64) ----------------
__global__ __launch_bounds__(256) void k_norm(const float* __restrict__ feat,
                                              double* __restrict__ inv_norm) {
  int lane = threadIdx.x & 63;
  int wid = threadIdx.x >> 6;
  int p = blockIdx.x * 4 + wid; // one wave per point
  const float4 v = *(const float4*)(feat + (size_t)p * DIM + lane * 4);
  double s = (double)v.x * v.x + (double)v.y * v.y + (double)v.z * v.z + (double)v.w * v.w;
#pragma unroll
  for (int m = 32; m; m >>= 1) s += __shfl_xor(s, m);
  if (lane == 0) inv_norm[p] = 1.0 / fmax(sqrt(s), 1e-12);
}

__device__ __forceinline__ double block_sum_256(double v, double* red) {
#pragma unroll
  for (int m = 32; m; m >>= 1) v += __shfl_xor(v, m);
  int w = threadIdx.x >> 6;
  if ((threadIdx.x & 63) == 0) red[w] = v;
  __syncthreads();
  return red[0] + red[1] + red[2] + red[3];
}

// ---------------- K0b: initial centers (f64 + f32 [d][k]) + c_sq32 --------
// init_idx = floor(linspace(0, N-1, K)): idx_k = floor(k*4095/23).
__global__ __launch_bounds__(256) void k_init_centers(const float* __restrict__ feat,
                                                      const double* __restrict__ inv_norm,
                                                      double* __restrict__ centers,
                                                      float* __restrict__ cT32,
                                                      float* __restrict__ c_sq32) {
  __shared__ double red[4];
  int t = threadIdx.x, k = blockIdx.x, b = blockIdx.y;
  int idx = (int)((double)k * (NPTS - 1) / (NSLOT - 1));
  double v = (double)feat[((size_t)b * NPTS + idx) * DIM + t] * inv_norm[b * NPTS + idx];
  centers[((size_t)b * NSLOT + k) * DIM + t] = v;
  cT32[((size_t)b * DIM + t) * NSLOT + k] = (float)v;
  double s = block_sum_256(v * v, red);
  if (t == 0) c_sq32[b * NSLOT + k] = (float)s;
}

// ---------------- K0c: tiled transpose feat -> xT[b][d][n] (f32) ----------
__global__ __launch_bounds__(256) void k_transpose(const float* __restrict__ feat,
                                                   float* __restrict__ xT) {
  __shared__ float tile[64][65];
  int ix = threadIdx.x & 63, iy = threadIdx.x >> 6;
  int bx = blockIdx.x, by = blockIdx.y, b = blockIdx.z;
  const float* fb = feat + ((size_t)b * NPTS + bx * 64) * DIM + by * 64;
#pragma unroll
  for (int r = 0; r < 64; r += 4)
    tile[r + iy][ix] = fb[(size_t)(r + iy) * DIM + ix];
  __syncthreads();
  float* xb = xT + ((size_t)b * DIM + by * 64) * NPTS + bx * 64;
#pragma unroll
  for (int r = 0; r < 64; r += 4)
    xb[(size_t)(r + iy) * NPTS + ix] = tile[ix][r + iy];
}

// ---------------- K1: assignment (f32 scoring), quarter-D per wave --------
// Unchanged from rounds 5-8 (bit-identical scores).
template <bool USE_T>
__global__ __launch_bounds__(256) void k_assign(const float* __restrict__ feat,
                                                const float* __restrict__ xT,
                                                const double* __restrict__ inv_norm,
                                                const float* __restrict__ cT32,
                                                const float* __restrict__ c_sq32,
                                                int* __restrict__ assign) {
  __shared__ float part[3][64][NSLOT + 1]; // 19200 B, odd lane stride
  int lane = threadIdx.x & 63;
  int q = __builtin_amdgcn_readfirstlane(threadIdx.x >> 6);
  int blk = blockIdx.x, b = blockIdx.y;
  int n = blk * 64 + lane;
  const float* cb = cT32 + ((size_t)b * DIM + q * 64) * NSLOT;

  float dot[NSLOT];
#pragma unroll
  for (int k = 0; k < NSLOT; ++k) dot[k] = 0.0f;

  for (int d = 0; d < 64; d += 8) {
    float x[8];
    if (USE_T) {
      const float* xp = xT + ((size_t)b * DIM + q * 64 + d) * NPTS + n;
#pragma unroll
      for (int j = 0; j < 8; ++j) x[j] = xp[(size_t)j * NPTS];
    } else {
      float4 v = *(const float4*)(feat + ((size_t)b * NPTS + n) * DIM + q * 64 + d);
      float4 u = *(const float4*)(feat + ((size_t)b * NPTS + n) * DIM + q * 64 + d + 4);
      x[0] = v.x; x[1] = v.y; x[2] = v.z; x[3] = v.w;
      x[4] = u.x; x[5] = u.y; x[6] = u.z; x[7] = u.w;
    }
    const float* cp = cb + (size_t)d * NSLOT; // wave-uniform -> s_load
#pragma unroll
    for (int k = 0; k < NSLOT; ++k) {
      float s = dot[k];
#pragma unroll
      for (int j = 0; j < 8; ++j) s = fmaf(x[j], cp[j * NSLOT + k], s);
      dot[k] = s;
    }
  }

  if (q) {
#pragma unroll
    for (int k = 0; k < NSLOT; ++k) part[q - 1][lane][k] = dot[k];
  }
  __syncthreads();

  if (q == 0) {
    float inv = (float)inv_norm[b * NPTS + n];
    const float* csq = c_sq32 + b * NSLOT; // uniform -> s_load
    int a = 0;
    float best = 0.0f;
#pragma unroll
    for (int k = 0; k < NSLOT; ++k) {
      float df = dot[k] + part[0][lane][k] + part[1][lane][k] + part[2][lane][k];
      float s = csq[k] - 2.0f * (df * inv);
      if (k == 0) { best = s; }
      else if (s < best) { best = s; a = k; }
    }
    assign[b * NPTS + n] = a;
  }
}

// ---------------- K2: streamed LDS-bucket partial sums ----------------
// Block (ch, b): rows [ch*256, ch*256+256), ascending. Thread t = dim t.
// part[a][t] += x * inv in LDS; waves own disjoint dim ranges -> no races;
// per-dim order = row order -> deterministic. Unroll x4 for load pipelining.
__global__ __launch_bounds__(256) void k_clusterS(const float* __restrict__ feat,
                                                  const double* __restrict__ inv_norm,
                                                  const int* __restrict__ assign,
                                                  double* __restrict__ psumG) {
  __shared__ double part[NSLOT * DIM]; // 48 KB
  __shared__ int a_lds[CPTS];
  __shared__ double i_lds[CPTS];
  int t = threadIdx.x, ch = blockIdx.x, b = blockIdx.y;

  a_lds[t] = assign[b * NPTS + ch * CPTS + t];
  i_lds[t] = inv_norm[b * NPTS + ch * CPTS + t];
#pragma unroll
  for (int i = 0; i < NSLOT; ++i) part[i * DIM + t] = 0.0;
  __syncthreads();

  const float* fb = feat + ((size_t)b * NPTS + ch * CPTS) * DIM + t;
  for (int row = 0; row < CPTS; row += 4) {
    float x0 = fb[(size_t)(row + 0) * DIM];
    float x1 = fb[(size_t)(row + 1) * DIM];
    float x2 = fb[(size_t)(row + 2) * DIM];
    float x3 = fb[(size_t)(row + 3) * DIM];
    int a0 = __builtin_amdgcn_readfirstlane(a_lds[row + 0]);
    int a1 = __builtin_amdgcn_readfirstlane(a_lds[row + 1]);
    int a2 = __builtin_amdgcn_readfirstlane(a_lds[row + 2]);
    int a3 = __builtin_amdgcn_readfirstlane(a_lds[row + 3]);
    double v0 = (double)x0 * i_lds[row + 0];
    double v1 = (double)x1 * i_lds[row + 1];
    double v2 = (double)x2 * i_lds[row + 2];
    double v3 = (double)x3 * i_lds[row + 3];
    part[a0 * DIM + t] += v0;
    part[a1 * DIM + t] += v1;
    part[a2 * DIM + t] += v2;
    part[a3 * DIM + t] += v3;
  }
  __syncthreads();

  double* ps = psumG + (size_t)(b * NCH + ch) * NSLOT * DIM;
#pragma unroll
  for (int i = 0; i < NSLOT; ++i) ps[i * DIM + t] = part[i * DIM + t];
}

// ---------------- K3: combine chunks + exact counts -> new centers --------
__global__ __launch_bounds__(256) void k_upd3(const double* __restrict__ psumG,
                                              const int* __restrict__ assign,
                                              double* __restrict__ centers,
                                              float* __restrict__ cT32,
                                              float* __restrict__ c_sq32) {
  __shared__ double red[4];
  __shared__ int scnt;
  int t = threadIdx.x, k = blockIdx.x, b = blockIdx.y;
  if (t == 0) scnt = 0;
  __syncthreads();

  double s = 0.0; // fixed ascending chunk order
#pragma unroll
  for (int ch = 0; ch < NCH; ++ch)
    s += psumG[((size_t)(b * NCH + ch) * NSLOT + k) * DIM + t];

  // exact integer counts from assignments (order-free)
  int c_loc = 0;
  const int* ab = assign + b * NPTS;
#pragma unroll
  for (int j = 0; j < NPTS / 256; ++j) c_loc += (ab[t + j * 256] == k) ? 1 : 0;
#pragma unroll
  for (int m = 32; m; m >>= 1) c_loc += __shfl_xor(c_loc, m);
  if ((t & 63) == 0) atomicAdd(&scnt, c_loc);
  __syncthreads();
  int cnt = scnt;

  size_t ci = ((size_t)b * NSLOT + k) * DIM + t;
  double nc = (cnt > 0) ? (s / (double)cnt) : centers[ci];
  centers[ci] = nc;
  cT32[((size_t)b * DIM + t) * NSLOT + k] = (float)nc;
  double sq = block_sum_256(nc * nc, red);
  if (t == 0) c_sq32[b * NSLOT + k] = (float)sq;
}

// ---------------- K4: masks + centers output ----------------
__global__ __launch_bounds__(256) void k_mask(const int* __restrict__ assign,
                                              float* __restrict__ masks) {
  int t = threadIdx.x, nc = blockIdx.x, k = blockIdx.y, b = blockIdx.z;
  int n = nc * 256 + t;
  masks[((size_t)b * NSLOT + k) * NPTS + n] = (assign[b * NPTS + n] == k) ? 1.0f : 0.0f;
}

__global__ __launch_bounds__(256) void k_copyc(const double* __restrict__ centers,
                                               float* __restrict__ out_centers) {
  int t = threadIdx.x, k = blockIdx.x, b = blockIdx.y;
  size_t i = ((size_t)b * NSLOT + k) * DIM + t;
  out_centers[i] = (float)centers[i];
}

extern "C" void kernel_launch(void* const* d_in, const int* in_sizes, int n_in,
                              void* d_out, int out_size, void* d_ws, size_t ws_size,
                              hipStream_t stream) {
  (void)in_sizes; (void)n_in; (void)out_size;
  const float* feat = (const float*)d_in[0];
  float* out_centers = (float*)d_out;                           // (32,24,256)
  float* out_masks = out_centers + (size_t)BATCH * NSLOT * DIM; // (32,24,4096)

  // workspace: ~29 MB fixed + optional 134 MB xT tail.
  char* ws = (char*)d_ws;
  double* inv_norm = (double*)ws; ws += (size_t)BATCH * NPTS * 8;              // 1.0 MB
  double* centers  = (double*)ws; ws += (size_t)BATCH * NSLOT * DIM * 8;       // 1.5 MB
  float* cT32      = (float*)ws;  ws += (size_t)BATCH * DIM * NSLOT * 4;       // 0.77 MB
  float* c_sq32    = (float*)ws;  ws += (size_t)BATCH * NSLOT * 4;             // 3 KB
  int* assign      = (int*)ws;    ws += (size_t)BATCH * NPTS * 4;              // 0.5 MB
  double* psumG    = (double*)ws; ws += (size_t)BATCH * NCH * NSLOT * DIM * 8; // 25 MB
  float* xT        = (float*)ws;
  size_t need_xT = (size_t)(ws - (char*)d_ws) + (size_t)BATCH * DIM * NPTS * 4; // ~163 MB
  bool useT = ws_size >= need_xT;

  k_norm<<<BATCH * NPTS / 4, 256, 0, stream>>>(feat, inv_norm);
  k_init_centers<<<dim3(NSLOT, BATCH), 256, 0, stream>>>(feat, inv_norm, centers,
                                                         cT32, c_sq32);
  if (useT)
    k_transpose<<<dim3(NPTS / 64, DIM / 64, BATCH), 256, 0, stream>>>(feat, xT);

  for (int it = 0; it <= NITER; ++it) {
    if (useT)
      k_assign<true><<<dim3(NPTS / 64, BATCH), 256, 0, stream>>>(feat, xT, inv_norm,
                                                                 cT32, c_sq32, assign);
    else
      k_assign<false><<<dim3(NPTS / 64, BATCH), 256, 0, stream>>>(feat, xT, inv_norm,
                                                                  cT32, c_sq32, assign);
    if (it == NITER) break; // final assignment only
    k_clusterS<<<dim3(NCH, BATCH), 256, 0, stream>>>(feat, inv_norm, assign, psumG);
    k_upd3<<<dim3(NSLOT, BATCH), 256, 0, stream>>>(psumG, assign, centers, cT32, c_sq32);
  }

  k_mask<<<dim3(NPTS / 256, NSLOT, BATCH), 256, 0, stream>>>(assign, out_masks);
  k_copyc<<<dim3(NSLOT, BATCH), 256, 0, stream>>>(centers, out_centers);
}